// Round 8
// baseline (73.670 us; speedup 1.0000x reference)
//
#include <hip/hip_runtime.h>
#include <stdint.h>

#define NCONN 14
#define NSYM 6
#define BLOCK 256
#define GRID 768                      // 3 blocks/CU resident (46KB LDS), persistent
#define WPB (BLOCK / 64)
#define NWAVES (GRID * WPB)           // 3072
#define CHUNK 32                      // bodies per wave-iteration
#define SLICE_FLOATS (CHUNK * 45)     // 1440 floats = 5760 B per sub-slice
#define F4_PER_CHUNK (SLICE_FLOATS / 4)  // 360
#define NSLOTS 64

typedef const __attribute__((address_space(1))) void* gptr_t;
typedef __attribute__((address_space(3))) void* lptr_t;

// connection endpoints as float offsets (joint*3)
static constexpr int CA[NCONN] = {0,3,3,6,9,12,15,3,24,24,27,30,33,36};
static constexpr int CB[NCONN] = {3,6,9,12,15,18,21,24,27,30,33,36,39,42};
// loss_3: |L_in[MAPIN[s]] - L_tg[MAPTG[s]]| (sym pairs are themselves connections)
static constexpr int MAPIN[NSYM] = {3,5,10,12,1,8};
static constexpr int MAPTG[NSYM] = {4,6,11,13,2,9};

#define WAIT_VM0()   do { asm volatile("s_waitcnt vmcnt(0)" ::: "memory"); __builtin_amdgcn_sched_barrier(0); } while (0)
#define WAIT_LGKM0() do { asm volatile("s_waitcnt lgkmcnt(0)" ::: "memory"); __builtin_amdgcn_sched_barrier(0); } while (0)

// Stage one 32-body chunk (1440 floats = 360 float4) of array g into a sub-slice.
__device__ __forceinline__ void stage32(const float* __restrict__ g, long long f4base,
                                        float* sf, int lane) {
    const float4* src = (const float4*)g + f4base + lane;
#pragma unroll
    for (int it = 0; it < 5; ++it) {
        __builtin_amdgcn_global_load_lds((gptr_t)(const void*)(src + it * 64),
                                         (lptr_t)(void*)(sf + it * 256 + lane * 4),
                                         16, 0, 0);
    }
    if (lane < 40) {   // f4 320..359
        __builtin_amdgcn_global_load_lds((gptr_t)(const void*)(src + 5 * 64),
                                         (lptr_t)(void*)(sf + 5 * 256 + lane * 4),
                                         16, 0, 0);
    }
}

__global__ void init_ws_kernel(double* ws) {
    int i = blockIdx.x * blockDim.x + threadIdx.x;
    if (i < NSLOTS * 8) ws[i] = 0.0;
}

__global__ __launch_bounds__(BLOCK, 3) void loss_main_kernel(
        const float* __restrict__ in, const float* __restrict__ tg,
        double* __restrict__ ws, int nChunks) {
    // per wave: separate in/tg sub-slices -> no slice reuse within an iteration,
    // so only ONE vmcnt(0) per iteration and 11.5KB in flight across the whole
    // compute phase (drain-shape fix; targets issued a full iteration earlier).
    __shared__ float lds[WPB][2][SLICE_FLOATS];   // 46080 B per block
    const int lane = threadIdx.x & 63;
    const int wid = threadIdx.x >> 6;
    float* sin_ = lds[wid][0];
    float* stg_ = lds[wid][1];
    const long long W = (long long)blockIdx.x * WPB + wid;
    const int rb = (lane & 31) * 45;           // lanes 32-63 broadcast-read lane&31's body
    const bool active = (lane < 32);

    float s1 = 0.f, s2 = 0.f, s3 = 0.f;

    long long c = W;
    if (c < nChunks) {
        stage32(in, c * F4_PER_CHUNK, sin_, lane);      // prologue: in(c)+tg(c) in flight
        stage32(tg, c * F4_PER_CHUNK, stg_, lane);
        for (; c < nChunks; c += NWAVES) {
            WAIT_VM0();                                  // in(c)+tg(c) arrived (issued ~1 iter ago)

            float xin[45];
#pragma unroll
            for (int k = 0; k < 45; ++k) xin[k] = sin_[rb + k];
            float xtg[45];
#pragma unroll
            for (int k = 0; k < 45; ++k) xtg[k] = stg_[rb + k];
            WAIT_LGKM0();                                // reads done -> slices reusable

            if (c + NWAVES < nChunks) {                  // prefetch next chunk-pair now;
                stage32(in, (c + NWAVES) * F4_PER_CHUNK, sin_, lane);   // stays in flight
                stage32(tg, (c + NWAVES) * F4_PER_CHUNK, stg_, lane);   // through all compute
            }

            float Lin[NCONN];
#pragma unroll
            for (int l = 0; l < NCONN; ++l) {
                const int a = CA[l], b = CB[l];
                Lin[l] = fabsf(xin[a] - xin[b]) + fabsf(xin[a+1] - xin[b+1]) + fabsf(xin[a+2] - xin[b+2]);
            }
            float t1 = 0.f;
#pragma unroll
            for (int k = 0; k < 45; ++k) t1 += fabsf(xin[k] - xtg[k]);

            float Ltg[NCONN];
#pragma unroll
            for (int l = 0; l < NCONN; ++l) {
                const int a = CA[l], b = CB[l];
                Ltg[l] = fabsf(xtg[a] - xtg[b]) + fabsf(xtg[a+1] - xtg[b+1]) + fabsf(xtg[a+2] - xtg[b+2]);
            }
            float t2 = 0.f;
#pragma unroll
            for (int l = 0; l < NCONN; ++l) t2 += fabsf(Lin[l] - Ltg[l]);
            float t3 = 0.f;
#pragma unroll
            for (int s = 0; s < NSYM; ++s) t3 += fabsf(Lin[MAPIN[s]] - Ltg[MAPTG[s]]);

            if (active) { s1 += t1; s2 += t2; s3 += t3; }
        }
    }

    // per-wave reduction (no cross-wave LDS, no barriers)
#pragma unroll
    for (int off = 32; off > 0; off >>= 1) {
        s1 += __shfl_down(s1, off);
        s2 += __shfl_down(s2, off);
        s3 += __shfl_down(s3, off);
    }
    if (lane == 0) {
        const int slot = (int)(W & (NSLOTS - 1));
        atomicAdd(&ws[slot * 8 + 0], (double)s1);
        atomicAdd(&ws[slot * 8 + 1], (double)s2);
        atomicAdd(&ws[slot * 8 + 2], (double)s3);
    }
}

__global__ void finalize_kernel(const double* __restrict__ ws, float* __restrict__ out,
                                long long nBodies, long long nFloats) {
    const int lane = threadIdx.x & 63;
    double a = 0.0, b = 0.0, d = 0.0;
    if (lane < NSLOTS) {
        a = ws[lane * 8 + 0];
        b = ws[lane * 8 + 1];
        d = ws[lane * 8 + 2];
    }
#pragma unroll
    for (int off = 32; off > 0; off >>= 1) {
        a += __shfl_down(a, off);
        b += __shfl_down(b, off);
        d += __shfl_down(d, off);
    }
    if (lane == 0) {
        double l1 = a / (double)nFloats;
        double l2 = b / (double)NCONN / (double)nBodies;
        double l3 = d / (double)NCONN / (double)nBodies;  // ref divides by n_conn
        out[0] = (float)(l1 + l2 + l3);
        out[1] = (float)l1;
        out[2] = (float)l2;
        out[3] = (float)l3;
    }
}

extern "C" void kernel_launch(void* const* d_in, const int* in_sizes, int n_in,
                              void* d_out, int out_size, void* d_ws, size_t ws_size,
                              hipStream_t stream) {
    const float* in = (const float*)d_in[0];
    const float* tg = (const float*)d_in[1];
    float* out = (float*)d_out;
    double* ws = (double*)d_ws;

    const long long nFloats = (long long)in_sizes[0];
    const long long nBodies = nFloats / 45;
    const int nChunks = (int)(nBodies / CHUNK);   // B=1e6 -> 31250 exact

    init_ws_kernel<<<1, 512, 0, stream>>>(ws);
    loss_main_kernel<<<GRID, BLOCK, 0, stream>>>(in, tg, ws, nChunks);
    finalize_kernel<<<1, 64, 0, stream>>>(ws, out, nBodies, nFloats);
}

// Round 12
// 70.521 us; speedup vs baseline: 1.0446x; 1.0446x over previous
//
#include <hip/hip_runtime.h>
#include <stdint.h>

#define NCONN 14
#define NSYM 6
#define BLOCK 256
#define GRID 768                      // persistent-ish: 3072 waves, blocks independent
#define WPB (BLOCK / 64)
#define NWAVES (GRID * WPB)
#define SLICE_FLOATS 3072             // 12288 B per wave slice (11520 used)
#define NSLOTS 64

typedef const __attribute__((address_space(1))) void* gptr_t;
typedef __attribute__((address_space(3))) void* lptr_t;

// connection endpoints as float offsets (joint*3)
static constexpr int CA[NCONN] = {0,3,3,6,9,12,15,3,24,24,27,30,33,36};
static constexpr int CB[NCONN] = {3,6,9,12,15,18,21,24,27,30,33,36,39,42};
// loss_3: |L_in[MAPIN[s]] - L_tg[MAPTG[s]]| (sym pairs are themselves connections)
static constexpr int MAPIN[NSYM] = {3,5,10,12,1,8};
static constexpr int MAPTG[NSYM] = {4,6,11,13,2,9};

#define WAIT_VM0()   do { asm volatile("s_waitcnt vmcnt(0)" ::: "memory"); __builtin_amdgcn_sched_barrier(0); } while (0)
#define WAIT_LGKM0() do { asm volatile("s_waitcnt lgkmcnt(0)" ::: "memory"); __builtin_amdgcn_sched_barrier(0); } while (0)

// Stage one 64-body chunk (2880 floats = 720 float4) of array g into this wave's slice.
__device__ __forceinline__ void stage64(const float* __restrict__ g, long long f4base,
                                        float* sf, int lane) {
    const float4* src = (const float4*)g + f4base + lane;
#pragma unroll
    for (int it = 0; it < 11; ++it) {
        __builtin_amdgcn_global_load_lds((gptr_t)(const void*)(src + it * 64),
                                         (lptr_t)(void*)(sf + it * 256 + lane * 4),
                                         16, 0, 0);
    }
    if (lane < 16) {   // f4 704..719
        __builtin_amdgcn_global_load_lds((gptr_t)(const void*)(src + 11 * 64),
                                         (lptr_t)(void*)(sf + 11 * 256 + lane * 4),
                                         16, 0, 0);
    }
}

__global__ void init_ws_kernel(double* ws) {
    int i = blockIdx.x * blockDim.x + threadIdx.x;
    if (i < NSLOTS * 8) ws[i] = 0.0;
}

__global__ __launch_bounds__(BLOCK, 3) void loss_main_kernel(
        const float* __restrict__ in, const float* __restrict__ tg,
        double* __restrict__ ws, int nChunks) {
    __shared__ float lds[WPB][SLICE_FLOATS];
    const int lane = threadIdx.x & 63;
    const int wid = threadIdx.x >> 6;
    float* sf = lds[wid];
    const long long W = (long long)blockIdx.x * WPB + wid;

    float s1 = 0.f, s2 = 0.f, s3 = 0.f;

    long long c = W;
    if (c < nChunks) {
        stage64(in, c * 720, sf, lane);                 // prologue: in(c) in flight
        for (; c < nChunks; c += NWAVES) {
            WAIT_VM0();                                  // in(c) arrived
            float xin[45];
            const int rb = lane * 45;
#pragma unroll
            for (int k = 0; k < 45; ++k) xin[k] = sf[rb + k];
            WAIT_LGKM0();                                // xin reads done -> slice reusable

            stage64(tg, c * 720, sf, lane);              // tg(c) in flight

            float Lin[NCONN];                            // hides tg flight
#pragma unroll
            for (int l = 0; l < NCONN; ++l) {
                const int a = CA[l], b = CB[l];
                Lin[l] = fabsf(xin[a] - xin[b]) + fabsf(xin[a+1] - xin[b+1]) + fabsf(xin[a+2] - xin[b+2]);
            }

            WAIT_VM0();                                  // tg(c) arrived
            float xtg[45];
#pragma unroll
            for (int k = 0; k < 45; ++k) xtg[k] = sf[rb + k];
            WAIT_LGKM0();                                // xtg reads done -> slice reusable

            if (c + NWAVES < nChunks)
                stage64(in, (c + NWAVES) * 720, sf, lane);  // prefetch next chunk

            float t1 = 0.f;                              // hides next-in flight
#pragma unroll
            for (int k = 0; k < 45; ++k) t1 += fabsf(xin[k] - xtg[k]);
            s1 += t1;

            float Ltg[NCONN];
#pragma unroll
            for (int l = 0; l < NCONN; ++l) {
                const int a = CA[l], b = CB[l];
                Ltg[l] = fabsf(xtg[a] - xtg[b]) + fabsf(xtg[a+1] - xtg[b+1]) + fabsf(xtg[a+2] - xtg[b+2]);
            }
            float t2 = 0.f;
#pragma unroll
            for (int l = 0; l < NCONN; ++l) t2 += fabsf(Lin[l] - Ltg[l]);
            s2 += t2;
            float t3 = 0.f;
#pragma unroll
            for (int s = 0; s < NSYM; ++s) t3 += fabsf(Lin[MAPIN[s]] - Ltg[MAPTG[s]]);
            s3 += t3;
        }
    }

    // per-wave reduction (no cross-wave LDS, no barriers)
#pragma unroll
    for (int off = 32; off > 0; off >>= 1) {
        s1 += __shfl_down(s1, off);
        s2 += __shfl_down(s2, off);
        s3 += __shfl_down(s3, off);
    }
    if (lane == 0) {
        const int slot = (int)(W & (NSLOTS - 1));
        atomicAdd(&ws[slot * 8 + 0], (double)s1);
        atomicAdd(&ws[slot * 8 + 1], (double)s2);
        atomicAdd(&ws[slot * 8 + 2], (double)s3);
    }
}

__global__ void finalize_kernel(const double* __restrict__ ws, float* __restrict__ out,
                                long long nBodies, long long nFloats) {
    const int lane = threadIdx.x & 63;
    double a = 0.0, b = 0.0, d = 0.0;
    if (lane < NSLOTS) {
        a = ws[lane * 8 + 0];
        b = ws[lane * 8 + 1];
        d = ws[lane * 8 + 2];
    }
#pragma unroll
    for (int off = 32; off > 0; off >>= 1) {
        a += __shfl_down(a, off);
        b += __shfl_down(b, off);
        d += __shfl_down(d, off);
    }
    if (lane == 0) {
        double l1 = a / (double)nFloats;
        double l2 = b / (double)NCONN / (double)nBodies;
        double l3 = d / (double)NCONN / (double)nBodies;  // ref divides by n_conn
        out[0] = (float)(l1 + l2 + l3);
        out[1] = (float)l1;
        out[2] = (float)l2;
        out[3] = (float)l3;
    }
}

extern "C" void kernel_launch(void* const* d_in, const int* in_sizes, int n_in,
                              void* d_out, int out_size, void* d_ws, size_t ws_size,
                              hipStream_t stream) {
    const float* in = (const float*)d_in[0];
    const float* tg = (const float*)d_in[1];
    float* out = (float*)d_out;
    double* ws = (double*)d_ws;

    const long long nFloats = (long long)in_sizes[0];
    const long long nBodies = nFloats / 45;
    const int nChunks = (int)(nBodies / 64);   // B=1e6 -> 15625 exact

    init_ws_kernel<<<1, 512, 0, stream>>>(ws);
    loss_main_kernel<<<GRID, BLOCK, 0, stream>>>(in, tg, ws, nChunks);
    finalize_kernel<<<1, 64, 0, stream>>>(ws, out, nBodies, nFloats);
}